// Round 1
// baseline (815.436 us; speedup 1.0000x reference)
//
#include <hip/hip_runtime.h>
#include <cstdint>

// MHA cross-attention: B=2, H=16, T=S=2048, D=64, E=1024, fp32 I/O.
// d_out: out[2][2048][1024] fp32, then attn[2][16][2048][2048] fp32.
//
// Round 3 changes vs 930.9us baseline:
//  - fused_attn: QK^T computed transposed (A=K, B=Q) so each lane owns 4
//    consecutive s values -> attn written as float4 (nontemporal, keeps K/V
//    resident in per-XCD L2), sP written as short4 (ds_write_b64).
//  - sP double-buffered -> one barrier per s-chunk (was two).
//  - q/k/v projections merged into one 768-block launch (was 3 serial
//    launches at 1 block/CU).
// PV path, ctx epilogue, GEMM tile structure unchanged (proven correct).

typedef __attribute__((ext_vector_type(8))) short short8;
typedef __attribute__((ext_vector_type(4))) short short4v;
typedef __attribute__((ext_vector_type(4))) float floatx4;

__device__ __forceinline__ short f2bf(float f) {
    union { float f; unsigned u; } c; c.f = f;
    unsigned r = c.u + 0x7FFFu + ((c.u >> 16) & 1u);  // RNE
    return (short)(r >> 16);
}

__device__ __forceinline__ void async_copy16(void* lds, const void* g) {
    __builtin_amdgcn_global_load_lds((const __attribute__((address_space(1))) void*)g,
                                     (__attribute__((address_space(3))) void*)lds,
                                     16, 0, 0);
}

// ---------------------------------------------------------------- cast kernel
__global__ __launch_bounds__(256) void cast_all(
    const float* __restrict__ a0, const float* __restrict__ a1,
    const float* __restrict__ a2, const float* __restrict__ a3,
    const float* __restrict__ a4, const float* __restrict__ a5,
    short* __restrict__ o0, short* __restrict__ o1, short* __restrict__ o2,
    short* __restrict__ o3, short* __restrict__ o4, short* __restrict__ o5)
{
    long i = ((long)blockIdx.x * 256 + threadIdx.x) * 8;
    const float* s; short* d; long off;
    if      (i <  4194304) { s = a0; d = o0; off = 0; }
    else if (i <  8388608) { s = a1; d = o1; off = 4194304; }
    else if (i <  9437184) { s = a2; d = o2; off = 8388608; }
    else if (i < 10485760) { s = a3; d = o3; off = 9437184; }
    else if (i < 11534336) { s = a4; d = o4; off = 10485760; }
    else                   { s = a5; d = o5; off = 11534336; }
    long j = i - off;
    float4 x0 = *(const float4*)(s + j);
    float4 x1 = *(const float4*)(s + j + 4);
    short8 r;
    r[0] = f2bf(x0.x); r[1] = f2bf(x0.y); r[2] = f2bf(x0.z); r[3] = f2bf(x0.w);
    r[4] = f2bf(x1.x); r[5] = f2bf(x1.y); r[6] = f2bf(x1.z); r[7] = f2bf(x1.w);
    *(short8*)(d + j) = r;
}

// ---------------------------------------------------------------- merged QKV
// One launch, 768 blocks: [0,256) q = xt@Wq^T (scale 1/8, head-major),
// [256,512) k = xs@Wk^T (head-major), [512,768) vT = Wv@xs^T ([bh][d][2048]).
// Tile code identical to gemm_bt: 128x128, BK=32, 4 waves 2x2 of 64x64.
__global__ __launch_bounds__(256) void proj_qkv(
    const short* __restrict__ xt, const short* __restrict__ xs,
    const short* __restrict__ wq, const short* __restrict__ wk,
    const short* __restrict__ wv,
    short* __restrict__ qb, short* __restrict__ kb, short* __restrict__ vtb)
{
    __shared__ __align__(16) short sA[128 * 32];
    __shared__ __align__(16) short sB[128 * 32];
    const int bid = blockIdx.x;
    const short *A, *Bm; short *outp; int mode; float scale; int bx, by;
    if (bid < 256)      { A = xt; Bm = wq; outp = qb;  mode = 0; scale = 0.125f;
                          bx = bid & 7;  by = bid >> 3; }
    else if (bid < 512) { int t = bid - 256; A = xs; Bm = wk; outp = kb;
                          mode = 0; scale = 1.0f; bx = t & 7;  by = t >> 3; }
    else                { int t = bid - 512; A = wv; Bm = xs; outp = vtb;
                          mode = 1; scale = 1.0f; bx = t & 31; by = t >> 5; }
    const int m0 = by * 128, n0 = bx * 128;
    const int tid = threadIdx.x;
    const int ln = tid & 15, qd = (tid & 63) >> 4, w = tid >> 6;
    const int wm = (w >> 1) * 64, wn = (w & 1) * 64;
    floatx4 acc[4][4] = {};

    for (int k0 = 0; k0 < 1024; k0 += 32) {
#pragma unroll
        for (int u = 0; u < 2; ++u) {
            int f = tid + u * 256;
            int row = f >> 2, ch = (f & 3) * 8;
            async_copy16(&sA[f * 8], A + (long)(m0 + row) * 1024 + k0 + ch);
            async_copy16(&sB[f * 8], Bm + (long)(n0 + row) * 1024 + k0 + ch);
        }
        __syncthreads();
        short8 a8[4], b8[4];
#pragma unroll
        for (int i = 0; i < 4; ++i)
            a8[i] = *(const short8*)&sA[(wm + i * 16 + ln) * 32 + qd * 8];
#pragma unroll
        for (int j = 0; j < 4; ++j)
            b8[j] = *(const short8*)&sB[(wn + j * 16 + ln) * 32 + qd * 8];
#pragma unroll
        for (int i = 0; i < 4; ++i)
#pragma unroll
            for (int j = 0; j < 4; ++j)
                acc[i][j] = __builtin_amdgcn_mfma_f32_16x16x32_bf16(
                    a8[i], b8[j], acc[i][j], 0, 0, 0);
        __syncthreads();
    }

#pragma unroll
    for (int i = 0; i < 4; ++i)
#pragma unroll
        for (int j = 0; j < 4; ++j)
#pragma unroll
            for (int r = 0; r < 4; ++r) {
                int gm = m0 + wm + i * 16 + qd * 4 + r;
                int gn = n0 + wn + j * 16 + ln;
                float val = acc[i][j][r];
                if (mode == 0) {
                    int bb = gm >> 11, t = gm & 2047, hh = gn >> 6, d = gn & 63;
                    outp[((((long)(bb * 16 + hh) << 11) | t) << 6) | d] =
                        f2bf(val * scale);
                } else {
                    int hh = gm >> 6, d = gm & 63, bb = gn >> 11, s = gn & 2047;
                    outp[(((long)((bb * 16 + hh) * 64 + d)) << 11) | s] = f2bf(val);
                }
            }
}

// ---------------------------------------------------------------- GEMM (B^T)
// MODE 3 only now: out = ctx @ Wo^T + bo, fp32 row-major.
template<int MODE>
__global__ __launch_bounds__(256) void gemm_bt(
    const short* __restrict__ A, const short* __restrict__ Bm,
    void* __restrict__ outp, const float* __restrict__ bias,
    int N, int K, int lda, int ldb, float scale)
{
    __shared__ __align__(16) short sA[128 * 32];
    __shared__ __align__(16) short sB[128 * 32];
    const int m0 = blockIdx.y * 128, n0 = blockIdx.x * 128;
    const int tid = threadIdx.x;
    const int ln = tid & 15, qd = (tid & 63) >> 4, w = tid >> 6;
    const int wm = (w >> 1) * 64, wn = (w & 1) * 64;
    floatx4 acc[4][4] = {};

    for (int k0 = 0; k0 < K; k0 += 32) {
#pragma unroll
        for (int u = 0; u < 2; ++u) {
            int f = tid + u * 256;
            int row = f >> 2, ch = (f & 3) * 8;
            async_copy16(&sA[f * 8], A + (long)(m0 + row) * lda + k0 + ch);
            async_copy16(&sB[f * 8], Bm + (long)(n0 + row) * ldb + k0 + ch);
        }
        __syncthreads();
        short8 a8[4], b8[4];
#pragma unroll
        for (int i = 0; i < 4; ++i)
            a8[i] = *(const short8*)&sA[(wm + i * 16 + ln) * 32 + qd * 8];
#pragma unroll
        for (int j = 0; j < 4; ++j)
            b8[j] = *(const short8*)&sB[(wn + j * 16 + ln) * 32 + qd * 8];
#pragma unroll
        for (int i = 0; i < 4; ++i)
#pragma unroll
            for (int j = 0; j < 4; ++j)
                acc[i][j] = __builtin_amdgcn_mfma_f32_16x16x32_bf16(
                    a8[i], b8[j], acc[i][j], 0, 0, 0);
        __syncthreads();
    }

#pragma unroll
    for (int i = 0; i < 4; ++i)
#pragma unroll
        for (int j = 0; j < 4; ++j)
#pragma unroll
            for (int r = 0; r < 4; ++r) {
                int gm = m0 + wm + i * 16 + qd * 4 + r;
                int gn = n0 + wn + j * 16 + ln;
                ((float*)outp)[(long)gm * N + gn] = acc[i][j][r] + bias[gn];
            }
}

// ---------------------------------------------------------------- fused attn
// Grid: x = mq*32 + bh (512 blocks; x%8 = bh%8 keeps a bh's K/V on one XCD).
// Block: 256 threads, 4 waves 2x2 over (t,s): wt=(w>>1)*64, ws=(w&1)*64.
// Scores computed TRANSPOSED: mfma(A=K_frag, B=Q_frag) -> per lane,
// acc[i][j][r] = score(s = s0+ws+i*16+qd*4+r, t = wt+j*16+ln): the 4 regs
// span 4 consecutive s -> float4 attn stores (nontemporal) + short4 sP writes.
// sP layout (frag-order, unchanged): P[t][s] at ((s>>3)*128 + t)*8 + (s&7).
// sP double-buffered -> single barrier per chunk.
__global__ __launch_bounds__(256) void fused_attn(
    const short* __restrict__ qb, const short* __restrict__ kb,
    const short* __restrict__ vtb, float* __restrict__ attn,
    short* __restrict__ ctx)
{
    const int bx = blockIdx.x;
    const int bh = bx & 31, mq = bx >> 5;
    const int b = bh >> 4, h = bh & 15;
    const int tid = threadIdx.x;
    const int ln = tid & 15, qd = (tid & 63) >> 4, w = tid >> 6;
    const int wt = (w >> 1) * 64;   // wave's t offset within 128-row tile
    const int ws = (w & 1) * 64;    // wave's s offset within 128-col chunk

    __shared__ __align__(16) short sP[2][16384];
    __shared__ float rpart[2][128];
    __shared__ float rinv[128];

    const short* qbase = qb + ((long)bh * 2048 + mq * 128) * 64;
    const short* kbase = kb + (long)bh * 2048 * 64;
    const short* vbase = vtb + (long)bh * 64 * 2048;
    float* abase = attn + ((long)bh * 2048 + mq * 128) * 2048;

    // Q fragments (B-operand), resident for both phases: rows t = wt+j*16+ln
    short8 a8q[4][2];
#pragma unroll
    for (int j = 0; j < 4; ++j)
#pragma unroll
        for (int ks = 0; ks < 2; ++ks)
            a8q[j][ks] = *(const short8*)(qbase + (wt + j * 16 + ln) * 64
                                          + ks * 32 + qd * 8);

    // ---- Phase 1: row sums of exp(scores) ----
    float sumP[4] = {};   // per j; lane's t = wt + j*16 + ln
    for (int s0 = 0; s0 < 2048; s0 += 128) {
        floatx4 acc[4][4] = {};
#pragma unroll
        for (int i = 0; i < 4; ++i) {
            const short* kp = kbase + (long)(s0 + ws + i * 16 + ln) * 64 + qd * 8;
            short8 bk0 = *(const short8*)kp;
            short8 bk1 = *(const short8*)(kp + 32);
#pragma unroll
            for (int j = 0; j < 4; ++j) {
                acc[i][j] = __builtin_amdgcn_mfma_f32_16x16x32_bf16(
                    bk0, a8q[j][0], acc[i][j], 0, 0, 0);
                acc[i][j] = __builtin_amdgcn_mfma_f32_16x16x32_bf16(
                    bk1, a8q[j][1], acc[i][j], 0, 0, 0);
            }
        }
#pragma unroll
        for (int i = 0; i < 4; ++i)
#pragma unroll
            for (int j = 0; j < 4; ++j)
#pragma unroll
                for (int r = 0; r < 4; ++r)
                    sumP[j] += __expf(acc[i][j][r]);
    }
    // reduce across the 4 qd lane-groups (s sub-blocks) sharing each t
#pragma unroll
    for (int j = 0; j < 4; ++j) {
        float v = sumP[j];
        v += __shfl_xor(v, 16);
        v += __shfl_xor(v, 32);
        if ((tid & 48) == 0) rpart[w & 1][wt + j * 16 + ln] = v;
    }
    __syncthreads();
    if (tid < 128) rinv[tid] = 1.0f / (rpart[0][tid] + rpart[1][tid]);
    __syncthreads();
    float invP[4];
#pragma unroll
    for (int j = 0; j < 4; ++j)
        invP[j] = rinv[wt + j * 16 + ln];

    // ---- Phase 2: recompute, write attn (nt float4), P@V ----
    floatx4 accO[2][4] = {};
    int nb = 0;
    for (int s0 = 0; s0 < 2048; s0 += 128, nb ^= 1) {
        floatx4 acc[4][4] = {};
#pragma unroll
        for (int i = 0; i < 4; ++i) {
            const short* kp = kbase + (long)(s0 + ws + i * 16 + ln) * 64 + qd * 8;
            short8 bk0 = *(const short8*)kp;
            short8 bk1 = *(const short8*)(kp + 32);
#pragma unroll
            for (int j = 0; j < 4; ++j) {
                acc[i][j] = __builtin_amdgcn_mfma_f32_16x16x32_bf16(
                    bk0, a8q[j][0], acc[i][j], 0, 0, 0);
                acc[i][j] = __builtin_amdgcn_mfma_f32_16x16x32_bf16(
                    bk1, a8q[j][1], acc[i][j], 0, 0, 0);
            }
        }
#pragma unroll
        for (int i = 0; i < 4; ++i) {
            const int sb  = ws + i * 16 + qd * 4;  // s within chunk, %4==0
            const int grp = sb >> 3;
            const int sub = sb & 7;                // (qd&1)*4
#pragma unroll
            for (int j = 0; j < 4; ++j) {
                const int t = wt + j * 16 + ln;
                floatx4 p4;
#pragma unroll
                for (int r = 0; r < 4; ++r)
                    p4[r] = __expf(acc[i][j][r]) * invP[j];
                short4v c4;
#pragma unroll
                for (int r = 0; r < 4; ++r) c4[r] = f2bf(p4[r]);
                *(short4v*)&sP[nb][(grp * 128 + t) * 8 + sub] = c4;
                __builtin_nontemporal_store(
                    p4, (floatx4*)(abase + (long)t * 2048 + s0 + sb));
            }
        }
        __syncthreads();  // sP[nb] writes visible; also orders next chunk's
                          // writes after this chunk's reads (dbuf => 1 barrier)
        // P @ V: wave w computes O rows w*32..w*32+31, all 64 d-cols
#pragma unroll
        for (int ks = 0; ks < 4; ++ks) {
            short8 a0 = *(const short8*)&sP[nb][((ks * 4 + qd) * 128 + w * 32 + ln) * 8];
            short8 a1 = *(const short8*)&sP[nb][((ks * 4 + qd) * 128 + w * 32 + 16 + ln) * 8];
#pragma unroll
            for (int j = 0; j < 4; ++j) {
                short8 bv = *(const short8*)(vbase + (long)(j * 16 + ln) * 2048
                                             + s0 + ks * 32 + qd * 8);
                accO[0][j] = __builtin_amdgcn_mfma_f32_16x16x32_bf16(
                    a0, bv, accO[0][j], 0, 0, 0);
                accO[1][j] = __builtin_amdgcn_mfma_f32_16x16x32_bf16(
                    a1, bv, accO[1][j], 0, 0, 0);
            }
        }
    }

    // write ctx (bf16 [b][t][h*64+d])
#pragma unroll
    for (int i2 = 0; i2 < 2; ++i2)
#pragma unroll
        for (int j = 0; j < 4; ++j)
#pragma unroll
            for (int r = 0; r < 4; ++r) {
                int t = mq * 128 + w * 32 + i2 * 16 + qd * 4 + r;
                int d = j * 16 + ln;
                ctx[((long)(b * 2048 + t)) * 1024 + h * 64 + d] =
                    f2bf(accO[i2][j][r]);
            }
}

// ---------------------------------------------------------------- launch
extern "C" void kernel_launch(void* const* d_in, const int* in_sizes, int n_in,
                              void* d_out, int out_size, void* d_ws, size_t ws_size,
                              hipStream_t stream)
{
    const float* src = (const float*)d_in[0];
    const float* tgt = (const float*)d_in[1];
    const float* Wq  = (const float*)d_in[2];
    const float* Wk  = (const float*)d_in[3];
    const float* Wv  = (const float*)d_in[4];
    const float* Wo  = (const float*)d_in[5];
    const float* bo  = (const float*)d_in[6];
    float* out  = (float*)d_out;                // [4096][1024]
    float* attn = out + 4194304;                // [32][2048][2048]

    char* ws = (char*)d_ws;
    short* xt  = (short*)(ws);                  // [4096][1024] bf16 target
    short* xs  = (short*)(ws + (8L  << 20));    // [4096][1024] bf16 source
    short* wq  = (short*)(ws + (16L << 20));
    short* wk  = (short*)(ws + (18L << 20));
    short* wv  = (short*)(ws + (20L << 20));
    short* wo  = (short*)(ws + (22L << 20));
    short* qb  = (short*)(ws + (24L << 20));    // [32][2048][64]
    short* kb  = (short*)(ws + (32L << 20));    // [32][2048][64]
    short* vtb = (short*)(ws + (40L << 20));    // [32][64][2048]
    short* ctx = (short*)(ws);                  // reuse xt (dead after q GEMM)

    cast_all<<<6144, 256, 0, stream>>>(tgt, src, Wq, Wk, Wv, Wo,
                                       xt, xs, wq, wk, wv, wo);
    proj_qkv<<<768, 256, 0, stream>>>(xt, xs, wq, wk, wv, qb, kb, vtb);
    fused_attn<<<512, 256, 0, stream>>>(qb, kb, vtb, attn, ctx);
    gemm_bt<3><<<dim3(8, 32, 1), 256, 0, stream>>>(ctx, wo, out, bo,
                                          1024, 1024, 1024, 1024, 1.0f);
}